// Round 2
// baseline (394.711 us; speedup 1.0000x reference)
//
#include <hip/hip_runtime.h>
#include <hip/hip_bf16.h>
#include <math.h>

typedef __bf16 bf16;
typedef __bf16 bf16x8 __attribute__((ext_vector_type(8)));
typedef float  f32x4  __attribute__((ext_vector_type(4)));

#define MFMA(a,b,c) __builtin_amdgcn_mfma_f32_16x16x32_bf16((a),(b),(c),0,0,0)

// ---------------------------------------------------------------------------
// Dtype detection: read w_q_b (bias, |x| <~ 0.08) as raw bf16 halves.
// If the buffer is fp32, even positions are float low-mantissa garbage ->
// some of first 128 values will be huge/NaN. flag=1 -> inputs are fp32.
// ---------------------------------------------------------------------------
__global__ void detect_kernel(const unsigned short* __restrict__ wqb,
                              int* __restrict__ flag) {
  __shared__ int s;
  if (threadIdx.x == 0) s = 0;
  __syncthreads();
  const float x = __uint_as_float(((unsigned)wqb[threadIdx.x]) << 16);
  if (!(fabsf(x) <= 0.5f)) atomicOr(&s, 1);  // catches big AND NaN
  __syncthreads();
  if (threadIdx.x == 0) *flag = s;
}

// Canonicalize an input tensor to bf16 regardless of source dtype.
__global__ void cvt_kernel(const void* __restrict__ src, bf16* __restrict__ dst,
                           int n, const int* __restrict__ flag) {
  const int isf = *flag;
  for (int i = blockIdx.x * blockDim.x + threadIdx.x; i < n;
       i += gridDim.x * blockDim.x) {
    float v;
    if (isf) v = ((const float*)src)[i];
    else v = __uint_as_float(((unsigned)((const unsigned short*)src)[i]) << 16);
    dst[i] = (bf16)v;
  }
}

// ---------------------------------------------------------------------------
// Shared 128x128-tile GEMM core: Y[M,N] = X[M,K] @ W[N,K]^T, K=1024.
// ---------------------------------------------------------------------------
static __device__ __forceinline__ void gemm128_core(
    const bf16* __restrict__ X, const bf16* __restrict__ W,
    int bm, int bn, f32x4 acc[4][4])
{
  __shared__ __align__(16) bf16 Als[128][72];
  __shared__ __align__(16) bf16 Bls[128][72];
  const int t    = threadIdx.x;
  const int lane = t & 63;
  const int w    = t >> 6;
  const int wr   = w >> 1, wc = w & 1;
  const int fr   = lane & 15;
  const int fq   = lane >> 4;
  const int ldr  = t >> 3;
  const int ldc  = (t & 7) * 8;

  #pragma unroll
  for (int m = 0; m < 4; ++m)
    #pragma unroll
    for (int n = 0; n < 4; ++n)
      acc[m][n] = (f32x4){0.f, 0.f, 0.f, 0.f};

  for (int k0 = 0; k0 < 1024; k0 += 64) {
    __syncthreads();
    #pragma unroll
    for (int p = 0; p < 4; ++p) {
      const int row = p * 32 + ldr;
      *(bf16x8*)&Als[row][ldc] =
          *(const bf16x8*)&X[(size_t)(bm + row) * 1024 + k0 + ldc];
      *(bf16x8*)&Bls[row][ldc] =
          *(const bf16x8*)&W[(size_t)(bn + row) * 1024 + k0 + ldc];
    }
    __syncthreads();
    #pragma unroll
    for (int kk = 0; kk < 64; kk += 32) {
      bf16x8 a[4], b[4];
      #pragma unroll
      for (int m = 0; m < 4; ++m)
        a[m] = *(const bf16x8*)&Als[wr * 64 + m * 16 + fr][kk + fq * 8];
      #pragma unroll
      for (int n = 0; n < 4; ++n)
        b[n] = *(const bf16x8*)&Bls[wc * 64 + n * 16 + fr][kk + fq * 8];
      #pragma unroll
      for (int m = 0; m < 4; ++m)
        #pragma unroll
        for (int n = 0; n < 4; ++n)
          acc[m][n] = MFMA(a[m], b[n], acc[m][n]);
    }
  }
}

// ---------------------------------------------------------------------------
// QKV projection. grid = (32, 8, 3). z: 0->Q, 1->K ([B,H,L,64]), 2->V^T.
// ---------------------------------------------------------------------------
__global__ __launch_bounds__(256, 2) void qkv_kernel(
    const bf16* __restrict__ X,
    const bf16* __restrict__ Wq, const bf16* __restrict__ bq,
    const bf16* __restrict__ Wk, const bf16* __restrict__ bk,
    const bf16* __restrict__ Wv, const bf16* __restrict__ bv,
    bf16* __restrict__ Qo, bf16* __restrict__ Ko, bf16* __restrict__ Vto)
{
  const bf16 *W, *bias;
  bf16 *out;
  const int z = blockIdx.z;
  if (z == 0)      { W = Wq; bias = bq; out = Qo;  }
  else if (z == 1) { W = Wk; bias = bk; out = Ko;  }
  else             { W = Wv; bias = bv; out = Vto; }

  const int bm = blockIdx.x * 128, bn = blockIdx.y * 128;
  f32x4 acc[4][4];
  gemm128_core(X, W, bm, bn, acc);

  const int t = threadIdx.x, lane = t & 63, w = t >> 6;
  const int wr = w >> 1, wc = w & 1;
  const int fr = lane & 15, fq = lane >> 4;

  #pragma unroll
  for (int n = 0; n < 4; ++n) {
    const int col = bn + wc * 64 + n * 16 + fr;
    const float bb = (float)bias[col];
    const int h = col >> 6, d = col & 63;
    #pragma unroll
    for (int m = 0; m < 4; ++m) {
      #pragma unroll
      for (int r = 0; r < 4; ++r) {
        const int row = bm + wr * 64 + m * 16 + fq * 4 + r;
        const int b = row >> 11, li = row & 2047;
        const float v = acc[m][n][r] + bb;
        if (z != 2)
          out[(size_t)((b * 16 + h) * 2048 + li) * 64 + d] = (bf16)v;
        else
          out[(size_t)((b * 16 + h) * 64 + d) * 2048 + li] = (bf16)v;
      }
    }
  }
}

// ---------------------------------------------------------------------------
// Causal flash attention. grid = (32 qtiles, 32 bh). 4 waves x 16 q-rows.
// NaN-proofed online softmax: exp args clamped <= 0, guarded divide.
// ---------------------------------------------------------------------------
__global__ __launch_bounds__(256, 2) void attn_kernel(
    const bf16* __restrict__ Q, const bf16* __restrict__ K,
    const bf16* __restrict__ Vt, bf16* __restrict__ CTX)
{
  const int qi = 31 - (int)blockIdx.x;
  const int bh = blockIdx.y;
  const int t = threadIdx.x, lane = t & 63, w = t >> 6;
  const int fr = lane & 15, fq = lane >> 4;
  const bf16* Qb = Q  + (size_t)bh * 2048 * 64;
  const bf16* Kb = K  + (size_t)bh * 2048 * 64;
  const bf16* Vb = Vt + (size_t)bh * 64 * 2048;
  const int q0 = qi * 64 + w * 16;

  bf16x8 qf[2];
  #pragma unroll
  for (int j = 0; j < 2; ++j)
    qf[j] = *(const bf16x8*)&Qb[(size_t)(q0 + fr) * 64 + j * 32 + fq * 8];

  f32x4 o[4];
  #pragma unroll
  for (int g = 0; g < 4; ++g) o[g] = (f32x4){0.f, 0.f, 0.f, 0.f};
  float mrow[4] = {-30000.f, -30000.f, -30000.f, -30000.f};
  float srow[4] = {0.f, 0.f, 0.f, 0.f};

  __shared__ __align__(16) bf16 Pls[4][16][72];

  for (int kt = 0; kt <= qi; ++kt) {
    const int kbase = kt * 64;
    f32x4 S[4];
    #pragma unroll
    for (int g = 0; g < 4; ++g) {
      bf16x8 kf0 = *(const bf16x8*)&Kb[(size_t)(kbase + g * 16 + fr) * 64 + fq * 8];
      bf16x8 kf1 = *(const bf16x8*)&Kb[(size_t)(kbase + g * 16 + fr) * 64 + 32 + fq * 8];
      f32x4 s = (f32x4){0.f, 0.f, 0.f, 0.f};
      s = MFMA(qf[0], kf0, s);
      s = MFMA(qf[1], kf1, s);
      S[g] = s;
    }
    #pragma unroll
    for (int r = 0; r < 4; ++r) {
      const int qrow = q0 + fq * 4 + r;
      float mx = mrow[r];
      #pragma unroll
      for (int g = 0; g < 4; ++g) {
        float sv = S[g][r] * 0.125f;
        sv = (kbase + g * 16 + fr <= qrow) ? sv : -30000.0f;
        S[g][r] = sv;
        mx = fmaxf(mx, sv);
      }
      mx = fmaxf(mx, __shfl_xor(mx, 1));
      mx = fmaxf(mx, __shfl_xor(mx, 2));
      mx = fmaxf(mx, __shfl_xor(mx, 4));
      mx = fmaxf(mx, __shfl_xor(mx, 8));
      const float f = __expf(fminf(mrow[r] - mx, 0.f));
      mrow[r] = mx;
      float ps = 0.f;
      #pragma unroll
      for (int g = 0; g < 4; ++g) {
        const float p = __expf(fminf(S[g][r] - mx, 0.f));
        S[g][r] = p;
        ps += p;
      }
      ps += __shfl_xor(ps, 1);
      ps += __shfl_xor(ps, 2);
      ps += __shfl_xor(ps, 4);
      ps += __shfl_xor(ps, 8);
      srow[r] = srow[r] * f + ps;
      #pragma unroll
      for (int g = 0; g < 4; ++g) o[g][r] *= f;
    }
    #pragma unroll
    for (int g = 0; g < 4; ++g)
      #pragma unroll
      for (int r = 0; r < 4; ++r)
        Pls[w][fq * 4 + r][g * 16 + fr] = (bf16)S[g][r];
    __syncthreads();
    #pragma unroll
    for (int kc = 0; kc < 64; kc += 32) {
      bf16x8 pa = *(const bf16x8*)&Pls[w][fr][kc + fq * 8];
      #pragma unroll
      for (int g2 = 0; g2 < 4; ++g2) {
        bf16x8 vf = *(const bf16x8*)&Vb[(size_t)(g2 * 16 + fr) * 2048 + kbase + kc + fq * 8];
        o[g2] = MFMA(pa, vf, o[g2]);
      }
    }
    __syncthreads();
  }
  const int b = bh >> 4, h = bh & 15;
  #pragma unroll
  for (int r = 0; r < 4; ++r) {
    const float inv = 1.f / fmaxf(srow[r], 1e-30f);
    const int tok = b * 2048 + q0 + fq * 4 + r;
    #pragma unroll
    for (int g2 = 0; g2 < 4; ++g2) {
      const int d = g2 * 16 + fr;
      CTX[(size_t)tok * 1024 + h * 64 + d] = (bf16)(o[g2][r] * inv);
    }
  }
}

// ---------------------------------------------------------------------------
// Output projection: out = ctx @ Wo^T + bo, dtype per flag. grid = (32, 8).
// ---------------------------------------------------------------------------
__global__ __launch_bounds__(256, 2) void out_kernel(
    const bf16* __restrict__ CTXi, const bf16* __restrict__ Wo,
    const bf16* __restrict__ bo, void* __restrict__ Y,
    const int* __restrict__ flag)
{
  const int isf = flag ? *flag : 0;
  const int bm = blockIdx.x * 128, bn = blockIdx.y * 128;
  f32x4 acc[4][4];
  gemm128_core(CTXi, Wo, bm, bn, acc);

  const int t = threadIdx.x, lane = t & 63, w = t >> 6;
  const int wr = w >> 1, wc = w & 1;
  const int fr = lane & 15, fq = lane >> 4;

  #pragma unroll
  for (int n = 0; n < 4; ++n) {
    const int col = bn + wc * 64 + n * 16 + fr;
    const float bb = (float)bo[col];
    #pragma unroll
    for (int m = 0; m < 4; ++m)
      #pragma unroll
      for (int r = 0; r < 4; ++r) {
        const int row = bm + wr * 64 + m * 16 + fq * 4 + r;
        const size_t idx = (size_t)row * 1024 + col;
        const float v = acc[m][n][r] + bb;
        if (isf) ((float*)Y)[idx] = v;
        else     ((bf16*)Y)[idx] = (bf16)v;
      }
  }
}

// ---------------------------------------------------------------------------
extern "C" void kernel_launch(void* const* d_in, const int* in_sizes, int n_in,
                              void* d_out, int out_size, void* d_ws, size_t ws_size,
                              hipStream_t stream) {
  char* ws = (char*)d_ws;
  const size_t MB = 1024 * 1024;

  if (ws_size >= 50 * MB) {
    int*  flag = (int*)ws;
    bf16* cX  = (bf16*)(ws + 1 * MB);
    bf16* cWq = (bf16*)(ws + 9 * MB);
    bf16* cWk = (bf16*)(ws + 11 * MB);
    bf16* cWv = (bf16*)(ws + 13 * MB);
    bf16* cWo = (bf16*)(ws + 15 * MB);
    bf16* cBq = (bf16*)(ws + 17 * MB);
    bf16* cBk = (bf16*)(ws + 17 * MB + 4096);
    bf16* cBv = (bf16*)(ws + 17 * MB + 8192);
    bf16* cBo = (bf16*)(ws + 17 * MB + 12288);
    bf16* Qw  = (bf16*)(ws + 18 * MB);
    bf16* Kw  = (bf16*)(ws + 26 * MB);
    bf16* Vt  = (bf16*)(ws + 34 * MB);
    bf16* CT  = (bf16*)(ws + 42 * MB);

    detect_kernel<<<1, 128, 0, stream>>>((const unsigned short*)d_in[2], flag);
    cvt_kernel<<<2048, 256, 0, stream>>>(d_in[0], cX, 4194304, flag);
    cvt_kernel<<<1024, 256, 0, stream>>>(d_in[1], cWq, 1048576, flag);
    cvt_kernel<<<4,    256, 0, stream>>>(d_in[2], cBq, 1024, flag);
    cvt_kernel<<<1024, 256, 0, stream>>>(d_in[3], cWk, 1048576, flag);
    cvt_kernel<<<4,    256, 0, stream>>>(d_in[4], cBk, 1024, flag);
    cvt_kernel<<<1024, 256, 0, stream>>>(d_in[5], cWv, 1048576, flag);
    cvt_kernel<<<4,    256, 0, stream>>>(d_in[6], cBv, 1024, flag);
    cvt_kernel<<<1024, 256, 0, stream>>>(d_in[7], cWo, 1048576, flag);
    cvt_kernel<<<4,    256, 0, stream>>>(d_in[8], cBo, 1024, flag);

    qkv_kernel<<<dim3(32, 8, 3), 256, 0, stream>>>(cX, cWq, cBq, cWk, cBk,
                                                   cWv, cBv, Qw, Kw, Vt);
    attn_kernel<<<dim3(32, 32), 256, 0, stream>>>(Qw, Kw, Vt, CT);
    out_kernel<<<dim3(32, 8), 256, 0, stream>>>(CT, cWo, cBo, d_out, flag);
  } else {
    // Fallback: assume native bf16 buffers, compact 32MB layout.
    bf16* Qw = (bf16*)(ws);
    bf16* Kw = (bf16*)(ws + 8 * MB);
    bf16* Vt = (bf16*)(ws + 16 * MB);
    bf16* CT = (bf16*)(ws + 24 * MB);
    qkv_kernel<<<dim3(32, 8, 3), 256, 0, stream>>>(
        (const bf16*)d_in[0], (const bf16*)d_in[1], (const bf16*)d_in[2],
        (const bf16*)d_in[3], (const bf16*)d_in[4], (const bf16*)d_in[5],
        (const bf16*)d_in[6], Qw, Kw, Vt);
    attn_kernel<<<dim3(32, 32), 256, 0, stream>>>(Qw, Kw, Vt, CT);
    out_kernel<<<dim3(32, 8), 256, 0, stream>>>(CT, (const bf16*)d_in[7],
                                                (const bf16*)d_in[8], d_out,
                                                (const int*)nullptr);
  }
}

// Round 3
// 311.500 us; speedup vs baseline: 1.2671x; 1.2671x over previous
//
#include <hip/hip_runtime.h>
#include <hip/hip_bf16.h>
#include <math.h>

typedef __bf16 bf16;
typedef __bf16 bf16x4 __attribute__((ext_vector_type(4)));
typedef __bf16 bf16x8 __attribute__((ext_vector_type(8)));
typedef float  f32x4  __attribute__((ext_vector_type(4)));

#define MFMA(a,b,c) __builtin_amdgcn_mfma_f32_16x16x32_bf16((a),(b),(c),0,0,0)

__device__ __forceinline__ void gload16(const bf16* g, bf16* l) {
  __builtin_amdgcn_global_load_lds(
      (const __attribute__((address_space(1))) void*)g,
      (__attribute__((address_space(3))) void*)l, 16, 0, 0);
}

// ---------------------------------------------------------------------------
// Dtype detection (verified round 2): inputs are fp32; flag=1 -> fp32.
// ---------------------------------------------------------------------------
__global__ void detect_kernel(const unsigned short* __restrict__ wqb,
                              int* __restrict__ flag) {
  __shared__ int s;
  if (threadIdx.x == 0) s = 0;
  __syncthreads();
  const float x = __uint_as_float(((unsigned)wqb[threadIdx.x]) << 16);
  if (!(fabsf(x) <= 0.5f)) atomicOr(&s, 1);
  __syncthreads();
  if (threadIdx.x == 0) *flag = s;
}

__global__ void cvt_kernel(const void* __restrict__ src, bf16* __restrict__ dst,
                           int n, const int* __restrict__ flag) {
  const int isf = *flag;
  for (int i = blockIdx.x * blockDim.x + threadIdx.x; i < n;
       i += gridDim.x * blockDim.x) {
    float v;
    if (isf) v = ((const float*)src)[i];
    else v = __uint_as_float(((unsigned)((const unsigned short*)src)[i]) << 16);
    dst[i] = (bf16)v;
  }
}

// All four 1024-element biases in one launch. dst: [4][1024].
__global__ void cvt_biases_kernel(const void* s0, const void* s1,
                                  const void* s2, const void* s3,
                                  bf16* __restrict__ dst,
                                  const int* __restrict__ flag) {
  const int isf = *flag;
  const int i = blockIdx.x * blockDim.x + threadIdx.x;
  if (i >= 4096) return;
  const void* srcs[4] = {s0, s1, s2, s3};
  const void* s = srcs[i >> 10];
  const int j = i & 1023;
  float v;
  if (isf) v = ((const float*)s)[j];
  else v = __uint_as_float(((unsigned)((const unsigned short*)s)[j]) << 16);
  dst[i] = (bf16)v;
}

// ---------------------------------------------------------------------------
// 128x128-tile GEMM core (m97 structure): Y[M,N] = X[M,K] @ W[N,K]^T, K=1024.
// Linear [128][64] LDS, async global_load_lds width-16, single-buffered.
// ---------------------------------------------------------------------------
static __device__ __forceinline__ void gemm128_core(
    const bf16* __restrict__ X, const bf16* __restrict__ W,
    int bm, int bn, f32x4 acc[4][4])
{
  __shared__ __align__(16) bf16 Als[128][64];
  __shared__ __align__(16) bf16 Bls[128][64];
  const int t    = threadIdx.x;
  const int lane = t & 63;
  const int w    = t >> 6;
  const int wr   = w >> 1, wc = w & 1;
  const int fr   = lane & 15;
  const int fq   = lane >> 4;
  const int lrow = lane >> 3;       // 0..7
  const int lcol = (lane & 7) * 8;  // element col in 64

  #pragma unroll
  for (int m = 0; m < 4; ++m)
    #pragma unroll
    for (int n = 0; n < 4; ++n)
      acc[m][n] = (f32x4){0.f, 0.f, 0.f, 0.f};

  for (int k0 = 0; k0 < 1024; k0 += 64) {
    __syncthreads();  // previous tile's reads complete before overwrite
    #pragma unroll
    for (int p = 0; p < 4; ++p) {
      const int rb = p * 32 + w * 8;  // wave-uniform row base (8 rows/inst)
      gload16(&X[(size_t)(bm + rb + lrow) * 1024 + k0 + lcol], &Als[rb][0]);
      gload16(&W[(size_t)(bn + rb + lrow) * 1024 + k0 + lcol], &Bls[rb][0]);
    }
    __syncthreads();  // vmcnt(0) drain + barrier: tile staged
    #pragma unroll
    for (int kk = 0; kk < 64; kk += 32) {
      bf16x8 a[4], b[4];
      #pragma unroll
      for (int m = 0; m < 4; ++m)
        a[m] = *(const bf16x8*)&Als[wr * 64 + m * 16 + fr][kk + fq * 8];
      #pragma unroll
      for (int n = 0; n < 4; ++n)
        b[n] = *(const bf16x8*)&Bls[wc * 64 + n * 16 + fr][kk + fq * 8];
      #pragma unroll
      for (int m = 0; m < 4; ++m)
        #pragma unroll
        for (int n = 0; n < 4; ++n)
          acc[m][n] = MFMA(a[m], b[n], acc[m][n]);
    }
  }
}

// ---------------------------------------------------------------------------
// QKV projection. grid = (32, 8, 3). z: 0->Q, 1->K ([B,H,L,64]), 2->V^T
// ([B,H,64,L], packed bf16x4 stores along tokens).
// ---------------------------------------------------------------------------
__global__ __launch_bounds__(256, 3) void qkv_kernel(
    const bf16* __restrict__ X,
    const bf16* __restrict__ Wq, const bf16* __restrict__ Wk,
    const bf16* __restrict__ Wv, const bf16* __restrict__ Bias,
    bf16* __restrict__ Qo, bf16* __restrict__ Ko, bf16* __restrict__ Vto)
{
  const bf16 *W, *bias;
  bf16 *out;
  const int z = blockIdx.z;
  if (z == 0)      { W = Wq; bias = Bias;        out = Qo;  }
  else if (z == 1) { W = Wk; bias = Bias + 1024; out = Ko;  }
  else             { W = Wv; bias = Bias + 2048; out = Vto; }

  const int bm = blockIdx.x * 128, bn = blockIdx.y * 128;
  f32x4 acc[4][4];
  gemm128_core(X, W, bm, bn, acc);

  const int t = threadIdx.x, lane = t & 63, w = t >> 6;
  const int wr = w >> 1, wc = w & 1;
  const int fr = lane & 15, fq = lane >> 4;

  #pragma unroll
  for (int n = 0; n < 4; ++n) {
    const int col = bn + wc * 64 + n * 16 + fr;   // feature index in E
    const float bb = (float)bias[col];
    const int h = col >> 6, d = col & 63;
    if (z != 2) {
      #pragma unroll
      for (int m = 0; m < 4; ++m)
        #pragma unroll
        for (int r = 0; r < 4; ++r) {
          const int row = bm + wr * 64 + m * 16 + fq * 4 + r;  // token
          const int b = row >> 11, li = row & 2047;
          out[(size_t)((b * 16 + h) * 2048 + li) * 64 + d] =
              (bf16)(acc[m][n][r] + bb);
        }
    } else {
      #pragma unroll
      for (int m = 0; m < 4; ++m) {
        const int tok0 = bm + wr * 64 + m * 16 + fq * 4;  // 4 consecutive
        const int b = tok0 >> 11, li0 = tok0 & 2047;
        bf16x4 pk = {(bf16)(acc[m][n][0] + bb), (bf16)(acc[m][n][1] + bb),
                     (bf16)(acc[m][n][2] + bb), (bf16)(acc[m][n][3] + bb)};
        *(bf16x4*)&out[(size_t)((b * 16 + h) * 64 + d) * 2048 + li0] = pk;
      }
    }
  }
}

// ---------------------------------------------------------------------------
// Causal flash attention, swapped QK^T. grid = (32 qtiles, 32 bh).
// 4 waves x 16 queries; K-tiles of 64. mfma(K,Q) -> lane owns one query's
// scores; in-register softmax; ZERO barriers (P buffer is per-wave).
// ---------------------------------------------------------------------------
__global__ __launch_bounds__(256, 4) void attn_kernel(
    const bf16* __restrict__ Q, const bf16* __restrict__ K,
    const bf16* __restrict__ Vt, bf16* __restrict__ CTX)
{
  const int qi = 31 - (int)blockIdx.x;
  const int bh = blockIdx.y;
  const int t = threadIdx.x, lane = t & 63, w = t >> 6;
  const int fr = lane & 15, fq = lane >> 4;
  const bf16* Qb = Q  + (size_t)bh * 2048 * 64;
  const bf16* Kb = K  + (size_t)bh * 2048 * 64;
  const bf16* Vb = Vt + (size_t)bh * 64 * 2048;
  const int q0 = qi * 64 + w * 16;
  const int myq = q0 + fr;          // this lane's query (for stats)

  __shared__ __align__(16) bf16 Pls[4][16][72];

  const bf16x8 qf0 = *(const bf16x8*)&Qb[(size_t)(q0 + fr) * 64 + fq * 8];
  const bf16x8 qf1 = *(const bf16x8*)&Qb[(size_t)(q0 + fr) * 64 + 32 + fq * 8];

  f32x4 o[4];
  #pragma unroll
  for (int g = 0; g < 4; ++g) o[g] = (f32x4){0.f, 0.f, 0.f, 0.f};
  float m_r = -1e9f, s_r = 0.f;

  for (int kt = 0; kt <= qi; ++kt) {
    const int kbase = kt * 64;
    // QK^T swapped: D[key][query]; lane holds keys {g*16+fq*4+r}, query fr.
    f32x4 S[4];
    #pragma unroll
    for (int g = 0; g < 4; ++g) {
      const bf16* kr = &Kb[(size_t)(kbase + g * 16 + fr) * 64];
      bf16x8 kf0 = *(const bf16x8*)&kr[fq * 8];
      bf16x8 kf1 = *(const bf16x8*)&kr[32 + fq * 8];
      f32x4 s = (f32x4){0.f, 0.f, 0.f, 0.f};
      s = MFMA(kf0, qf0, s);
      s = MFMA(kf1, qf1, s);
      S[g] = s;
    }
    // scale + causal mask + in-register max
    float mx = m_r;
    #pragma unroll
    for (int g = 0; g < 4; ++g)
      #pragma unroll
      for (int r = 0; r < 4; ++r) {
        float sv = S[g][r] * 0.125f;
        sv = (kbase + g * 16 + fq * 4 + r <= myq) ? sv : -1e9f;
        S[g][r] = sv;
        mx = fmaxf(mx, sv);
      }
    mx = fmaxf(mx, __shfl_xor(mx, 16));
    mx = fmaxf(mx, __shfl_xor(mx, 32));
    const float f = __expf(m_r - mx);
    m_r = mx;
    float ps = 0.f;
    #pragma unroll
    for (int g = 0; g < 4; ++g)
      #pragma unroll
      for (int r = 0; r < 4; ++r) {
        const float p = __expf(S[g][r] - mx);
        S[g][r] = p;
        ps += p;
      }
    ps += __shfl_xor(ps, 16);
    ps += __shfl_xor(ps, 32);
    s_r = s_r * f + ps;
    // broadcast rescale factor to the lanes that hold each query's O rows
    float frow[4];
    #pragma unroll
    for (int r = 0; r < 4; ++r) frow[r] = __shfl(f, fq * 4 + r, 64);
    #pragma unroll
    for (int g = 0; g < 4; ++g)
      #pragma unroll
      for (int r = 0; r < 4; ++r) o[g][r] *= frow[r];
    // P -> LDS: 4 packed b64 stores (keys fq*4+r consecutive), row = query
    #pragma unroll
    for (int g = 0; g < 4; ++g) {
      bf16x4 pk = {(bf16)S[g][0], (bf16)S[g][1], (bf16)S[g][2], (bf16)S[g][3]};
      *(bf16x4*)&Pls[w][fr][g * 16 + fq * 4] = pk;
    }
    // PV: o[q][d] += P[q][k] * Vt[d][k]  (same-wave LDS dep, no barrier)
    #pragma unroll
    for (int kc = 0; kc < 64; kc += 32) {
      bf16x8 pa = *(const bf16x8*)&Pls[w][fr][kc + fq * 8];
      #pragma unroll
      for (int g2 = 0; g2 < 4; ++g2) {
        bf16x8 vf = *(const bf16x8*)&Vb[(size_t)(g2 * 16 + fr) * 2048 +
                                        kbase + kc + fq * 8];
        o[g2] = MFMA(pa, vf, o[g2]);
      }
    }
  }
  const float inv = 1.f / fmaxf(s_r, 1e-30f);
  float invr[4];
  #pragma unroll
  for (int r = 0; r < 4; ++r) invr[r] = __shfl(inv, fq * 4 + r, 64);
  const int b = bh >> 4, h = bh & 15;
  #pragma unroll
  for (int r = 0; r < 4; ++r) {
    const int tok = b * 2048 + q0 + fq * 4 + r;
    #pragma unroll
    for (int g2 = 0; g2 < 4; ++g2)
      CTX[(size_t)tok * 1024 + h * 64 + g2 * 16 + fr] =
          (bf16)(o[g2][r] * invr[r]);
  }
}

// ---------------------------------------------------------------------------
// Output projection: out = ctx @ Wo^T + bo. grid = (32, 8).
// ---------------------------------------------------------------------------
__global__ __launch_bounds__(256, 3) void out_kernel(
    const bf16* __restrict__ CTXi, const bf16* __restrict__ Wo,
    const bf16* __restrict__ bo, void* __restrict__ Y,
    const int* __restrict__ flag)
{
  const int isf = *flag;
  const int bm = blockIdx.x * 128, bn = blockIdx.y * 128;
  f32x4 acc[4][4];
  gemm128_core(CTXi, Wo, bm, bn, acc);

  const int t = threadIdx.x, lane = t & 63, w = t >> 6;
  const int wr = w >> 1, wc = w & 1;
  const int fr = lane & 15, fq = lane >> 4;

  #pragma unroll
  for (int n = 0; n < 4; ++n) {
    const int col = bn + wc * 64 + n * 16 + fr;
    const float bb = (float)bo[col];
    #pragma unroll
    for (int m = 0; m < 4; ++m)
      #pragma unroll
      for (int r = 0; r < 4; ++r) {
        const int row = bm + wr * 64 + m * 16 + fq * 4 + r;
        const size_t idx = (size_t)row * 1024 + col;
        const float v = acc[m][n][r] + bb;
        if (isf) ((float*)Y)[idx] = v;
        else     ((bf16*)Y)[idx] = (bf16)v;
      }
  }
}

// ---------------------------------------------------------------------------
extern "C" void kernel_launch(void* const* d_in, const int* in_sizes, int n_in,
                              void* d_out, int out_size, void* d_ws, size_t ws_size,
                              hipStream_t stream) {
  char* ws = (char*)d_ws;
  const size_t MB = 1024 * 1024;

  int*  flag = (int*)ws;
  bf16* cX  = (bf16*)(ws + 1 * MB);
  bf16* cWq = (bf16*)(ws + 9 * MB);
  bf16* cWk = (bf16*)(ws + 11 * MB);
  bf16* cWv = (bf16*)(ws + 13 * MB);
  bf16* cWo = (bf16*)(ws + 15 * MB);
  bf16* cB  = (bf16*)(ws + 17 * MB);   // [4][1024]: q,k,v,o
  bf16* Qw  = (bf16*)(ws + 18 * MB);
  bf16* Kw  = (bf16*)(ws + 26 * MB);
  bf16* Vt  = (bf16*)(ws + 34 * MB);
  bf16* CT  = (bf16*)(ws + 42 * MB);

  detect_kernel<<<1, 128, 0, stream>>>((const unsigned short*)d_in[2], flag);
  cvt_kernel<<<2048, 256, 0, stream>>>(d_in[0], cX, 4194304, flag);
  cvt_kernel<<<1024, 256, 0, stream>>>(d_in[1], cWq, 1048576, flag);
  cvt_kernel<<<1024, 256, 0, stream>>>(d_in[3], cWk, 1048576, flag);
  cvt_kernel<<<1024, 256, 0, stream>>>(d_in[5], cWv, 1048576, flag);
  cvt_kernel<<<1024, 256, 0, stream>>>(d_in[7], cWo, 1048576, flag);
  cvt_biases_kernel<<<16, 256, 0, stream>>>(d_in[2], d_in[4], d_in[6], d_in[8],
                                            cB, flag);

  qkv_kernel<<<dim3(32, 8, 3), 256, 0, stream>>>(cX, cWq, cWk, cWv, cB,
                                                 Qw, Kw, Vt);
  attn_kernel<<<dim3(32, 32), 256, 0, stream>>>(Qw, Kw, Vt, CT);
  out_kernel<<<dim3(32, 8), 256, 0, stream>>>(CT, cWo, cB + 3072, d_out, flag);
}

// Round 4
// 161.089 us; speedup vs baseline: 2.4503x; 1.9337x over previous
//
#include <hip/hip_runtime.h>
#include <hip/hip_bf16.h>
#include <math.h>

typedef __bf16 bf16;
typedef __bf16 bf16x4 __attribute__((ext_vector_type(4)));
typedef __bf16 bf16x8 __attribute__((ext_vector_type(8)));
typedef float  f32x4  __attribute__((ext_vector_type(4)));
typedef float  float4v __attribute__((ext_vector_type(4)));
typedef unsigned short u16x4 __attribute__((ext_vector_type(4)));

#define MFMA(a,b,c) __builtin_amdgcn_mfma_f32_16x16x32_bf16((a),(b),(c),0,0,0)

__device__ __forceinline__ void gload16(const bf16* g, bf16* l) {
  __builtin_amdgcn_global_load_lds(
      (const __attribute__((address_space(1))) void*)g,
      (__attribute__((address_space(3))) void*)l, 16, 0, 0);
}

// ---------------------------------------------------------------------------
// Dtype detection (verified: inputs are fp32; flag=1 -> fp32).
// ---------------------------------------------------------------------------
__global__ void detect_kernel(const unsigned short* __restrict__ wqb,
                              int* __restrict__ flag) {
  __shared__ int s;
  if (threadIdx.x == 0) s = 0;
  __syncthreads();
  const float x = __uint_as_float(((unsigned)wqb[threadIdx.x]) << 16);
  if (!(fabsf(x) <= 0.5f)) atomicOr(&s, 1);
  __syncthreads();
  if (threadIdx.x == 0) *flag = s;
}

// ---------------------------------------------------------------------------
// One fused convert for all 9 inputs (float4-vectorized, grid-stride).
// ---------------------------------------------------------------------------
__global__ void cvt_all_kernel(const void* x, const void* wq, const void* wk,
                               const void* wv, const void* wo,
                               const void* bq, const void* bk, const void* bv,
                               const void* bo,
                               bf16* cX, bf16* cWq, bf16* cWk, bf16* cWv,
                               bf16* cWo, bf16* cB, const int* __restrict__ flag)
{
  const int isf = *flag;
  const int NX = 1048576, NW = 262144, NB = 256;  // in 4-element groups
  const int total = NX + 4 * NW + 4 * NB;
  for (int gid = blockIdx.x * blockDim.x + threadIdx.x; gid < total;
       gid += gridDim.x * blockDim.x) {
    const void* s; bf16* d; int off;
    if (gid < NX)                { s = x;  d = cX;  off = gid; }
    else if (gid < NX + NW)      { s = wq; d = cWq; off = gid - NX; }
    else if (gid < NX + 2 * NW)  { s = wk; d = cWk; off = gid - NX - NW; }
    else if (gid < NX + 3 * NW)  { s = wv; d = cWv; off = gid - NX - 2 * NW; }
    else if (gid < NX + 4 * NW)  { s = wo; d = cWo; off = gid - NX - 3 * NW; }
    else {
      const int r = gid - NX - 4 * NW;
      const int wb = r / NB; off = r % NB;
      s = (wb == 0) ? bq : (wb == 1) ? bk : (wb == 2) ? bv : bo;
      d = cB + wb * 1024;
    }
    float4v v;
    if (isf) v = ((const float4v*)s)[off];
    else {
      u16x4 u = ((const u16x4*)s)[off];
      v = (float4v){__uint_as_float((unsigned)u.x << 16),
                    __uint_as_float((unsigned)u.y << 16),
                    __uint_as_float((unsigned)u.z << 16),
                    __uint_as_float((unsigned)u.w << 16)};
    }
    bf16x4 ov = {(bf16)v.x, (bf16)v.y, (bf16)v.z, (bf16)v.w};
    *(bf16x4*)&d[off * 4] = ov;
  }
}

// ---------------------------------------------------------------------------
// 128x128-tile GEMM core (m97 structure): Y[M,N] = X[M,K] @ W[N,K]^T, K=1024.
// ---------------------------------------------------------------------------
static __device__ __forceinline__ void gemm128_core(
    const bf16* __restrict__ X, const bf16* __restrict__ W,
    int bm, int bn, f32x4 acc[4][4])
{
  __shared__ __align__(16) bf16 Als[128][64];
  __shared__ __align__(16) bf16 Bls[128][64];
  const int t    = threadIdx.x;
  const int lane = t & 63;
  const int w    = t >> 6;
  const int wr   = w >> 1, wc = w & 1;
  const int fr   = lane & 15;
  const int fq   = lane >> 4;
  const int lrow = lane >> 3;
  const int lcol = (lane & 7) * 8;

  #pragma unroll
  for (int m = 0; m < 4; ++m)
    #pragma unroll
    for (int n = 0; n < 4; ++n)
      acc[m][n] = (f32x4){0.f, 0.f, 0.f, 0.f};

  for (int k0 = 0; k0 < 1024; k0 += 64) {
    __syncthreads();
    #pragma unroll
    for (int p = 0; p < 4; ++p) {
      const int rb = p * 32 + w * 8;
      gload16(&X[(size_t)(bm + rb + lrow) * 1024 + k0 + lcol], &Als[rb][0]);
      gload16(&W[(size_t)(bn + rb + lrow) * 1024 + k0 + lcol], &Bls[rb][0]);
    }
    __syncthreads();
    #pragma unroll
    for (int kk = 0; kk < 64; kk += 32) {
      bf16x8 a[4], b[4];
      #pragma unroll
      for (int m = 0; m < 4; ++m)
        a[m] = *(const bf16x8*)&Als[wr * 64 + m * 16 + fr][kk + fq * 8];
      #pragma unroll
      for (int n = 0; n < 4; ++n)
        b[n] = *(const bf16x8*)&Bls[wc * 64 + n * 16 + fr][kk + fq * 8];
      #pragma unroll
      for (int m = 0; m < 4; ++m)
        #pragma unroll
        for (int n = 0; n < 4; ++n)
          acc[m][n] = MFMA(a[m], b[n], acc[m][n]);
    }
  }
}

// ---------------------------------------------------------------------------
// QKV projection. grid = (32, 8, 3). z: 0->Q, 1->K ([B,H,L,64]), 2->V^T.
// ---------------------------------------------------------------------------
__global__ __launch_bounds__(256, 3) void qkv_kernel(
    const bf16* __restrict__ X,
    const bf16* __restrict__ Wq, const bf16* __restrict__ Wk,
    const bf16* __restrict__ Wv, const bf16* __restrict__ Bias,
    bf16* __restrict__ Qo, bf16* __restrict__ Ko, bf16* __restrict__ Vto)
{
  const bf16 *W, *bias;
  bf16 *out;
  const int z = blockIdx.z;
  if (z == 0)      { W = Wq; bias = Bias;        out = Qo;  }
  else if (z == 1) { W = Wk; bias = Bias + 1024; out = Ko;  }
  else             { W = Wv; bias = Bias + 2048; out = Vto; }

  const int bm = blockIdx.x * 128, bn = blockIdx.y * 128;
  f32x4 acc[4][4];
  gemm128_core(X, W, bm, bn, acc);

  const int t = threadIdx.x, lane = t & 63, w = t >> 6;
  const int wr = w >> 1, wc = w & 1;
  const int fr = lane & 15, fq = lane >> 4;

  #pragma unroll
  for (int n = 0; n < 4; ++n) {
    const int col = bn + wc * 64 + n * 16 + fr;
    const float bb = (float)bias[col];
    const int h = col >> 6, d = col & 63;
    if (z != 2) {
      #pragma unroll
      for (int m = 0; m < 4; ++m)
        #pragma unroll
        for (int r = 0; r < 4; ++r) {
          const int row = bm + wr * 64 + m * 16 + fq * 4 + r;
          const int b = row >> 11, li = row & 2047;
          out[(size_t)((b * 16 + h) * 2048 + li) * 64 + d] =
              (bf16)(acc[m][n][r] + bb);
        }
    } else {
      #pragma unroll
      for (int m = 0; m < 4; ++m) {
        const int tok0 = bm + wr * 64 + m * 16 + fq * 4;
        const int b = tok0 >> 11, li0 = tok0 & 2047;
        bf16x4 pk = {(bf16)(acc[m][n][0] + bb), (bf16)(acc[m][n][1] + bb),
                     (bf16)(acc[m][n][2] + bb), (bf16)(acc[m][n][3] + bb)};
        *(bf16x4*)&out[(size_t)((b * 16 + h) * 64 + d) * 2048 + li0] = pk;
      }
    }
  }
}

// ---------------------------------------------------------------------------
// Attention helpers: swizzled LDS tile stage (linear dest + inverse-swizzled
// global source, rule #21) and swizzled b128 read.
// ---------------------------------------------------------------------------
__device__ __forceinline__ void stage_tile(const bf16* __restrict__ gK,
                                           const bf16* __restrict__ gV,
                                           int kbase, bf16 (*Kl)[64],
                                           bf16 (*Vl)[64], int w, int lane) {
  const int r8 = lane >> 3;            // 0..7
  const int cb = (lane & 7) << 4;      // byte col 0..112
  #pragma unroll
  for (int p = 0; p < 2; ++p) {
    const int row = p * 32 + w * 8 + r8;
    const int sc = (cb ^ ((row & 7) << 4)) >> 1;  // element col, pre-swizzled
    gload16(&gK[(size_t)(kbase + row) * 64 + sc], &Kl[p * 32 + w * 8][0]);
    gload16(&gV[(size_t)row * 2048 + kbase + sc], &Vl[p * 32 + w * 8][0]);
  }
}

__device__ __forceinline__ bf16x8 swz_read(const bf16 (*Tl)[64], int row,
                                           int colb) {
  const char* p = (const char*)(&Tl[0][0]) + row * 128 +
                  (colb ^ ((row & 7) << 4));
  return *(const bf16x8*)p;
}

// ---------------------------------------------------------------------------
// Causal flash attention, swapped QK^T + LDS-staged K/V (2-phase pipeline).
// grid = (32 qtiles, 32 bh). 4 waves x 16 queries; K-tiles of 64 shared by
// all waves via double-buffered LDS.
// ---------------------------------------------------------------------------
__global__ __launch_bounds__(256, 3) void attn_kernel(
    const bf16* __restrict__ Q, const bf16* __restrict__ K,
    const bf16* __restrict__ Vt, bf16* __restrict__ CTX)
{
  const int qi = 31 - (int)blockIdx.x;  // heavy tiles first
  const int bh = blockIdx.y;
  const int t = threadIdx.x, lane = t & 63, w = t >> 6;
  const int fr = lane & 15, fq = lane >> 4;
  const bf16* Qb = Q  + (size_t)bh * 2048 * 64;
  const bf16* Kb = K  + (size_t)bh * 2048 * 64;
  const bf16* Vb = Vt + (size_t)bh * 64 * 2048;
  const int q0 = qi * 64 + w * 16;
  const int myq = q0 + fr;

  __shared__ __align__(16) bf16 Kls[2][64][64];  // 16 KB
  __shared__ __align__(16) bf16 Vls[2][64][64];  // 16 KB
  __shared__ __align__(16) bf16 Pls[4][16][72];  // 9 KB

  const bf16x8 qf0 = *(const bf16x8*)&Qb[(size_t)(q0 + fr) * 64 + fq * 8];
  const bf16x8 qf1 = *(const bf16x8*)&Qb[(size_t)(q0 + fr) * 64 + 32 + fq * 8];

  f32x4 o[4];
  #pragma unroll
  for (int g = 0; g < 4; ++g) o[g] = (f32x4){0.f, 0.f, 0.f, 0.f};
  float m_r = -1e9f, s_r = 0.f;

  stage_tile(Kb, Vb, 0, Kls[0], Vls[0], w, lane);
  __syncthreads();  // compiler drains vmcnt(0) before barrier: tile 0 ready
  int cur = 0;

  for (int kt = 0; kt <= qi; ++kt) {
    // issue next tile's async loads first (hide under compute)
    if (kt < qi)
      stage_tile(Kb, Vb, (kt + 1) * 64, Kls[cur ^ 1], Vls[cur ^ 1], w, lane);

    const int kbase = kt * 64;
    // QK^T swapped: D[key][query]; lane holds keys {g*16+fq*4+r}, query fr.
    f32x4 S[4];
    #pragma unroll
    for (int g = 0; g < 4; ++g) {
      const int kr = g * 16 + fr;
      bf16x8 kf0 = swz_read(Kls[cur], kr, fq * 16);
      bf16x8 kf1 = swz_read(Kls[cur], kr, 64 + fq * 16);
      f32x4 s = (f32x4){0.f, 0.f, 0.f, 0.f};
      s = MFMA(kf0, qf0, s);
      s = MFMA(kf1, qf1, s);
      S[g] = s;
    }
    // scale + causal mask + in-register online softmax
    float mx = m_r;
    #pragma unroll
    for (int g = 0; g < 4; ++g)
      #pragma unroll
      for (int r = 0; r < 4; ++r) {
        float sv = S[g][r] * 0.125f;
        sv = (kbase + g * 16 + fq * 4 + r <= myq) ? sv : -1e9f;
        S[g][r] = sv;
        mx = fmaxf(mx, sv);
      }
    mx = fmaxf(mx, __shfl_xor(mx, 16));
    mx = fmaxf(mx, __shfl_xor(mx, 32));
    const float f = __expf(m_r - mx);
    m_r = mx;
    float ps = 0.f;
    #pragma unroll
    for (int g = 0; g < 4; ++g)
      #pragma unroll
      for (int r = 0; r < 4; ++r) {
        const float p = __expf(S[g][r] - mx);
        S[g][r] = p;
        ps += p;
      }
    ps += __shfl_xor(ps, 16);
    ps += __shfl_xor(ps, 32);
    s_r = s_r * f + ps;
    float frow[4];
    #pragma unroll
    for (int r = 0; r < 4; ++r) frow[r] = __shfl(f, fq * 4 + r, 64);
    #pragma unroll
    for (int g = 0; g < 4; ++g)
      #pragma unroll
      for (int r = 0; r < 4; ++r) o[g][r] *= frow[r];
    // P -> per-wave LDS (packed b64), then PV from staged V^T
    #pragma unroll
    for (int g = 0; g < 4; ++g) {
      bf16x4 pk = {(bf16)S[g][0], (bf16)S[g][1], (bf16)S[g][2], (bf16)S[g][3]};
      *(bf16x4*)&Pls[w][fr][g * 16 + fq * 4] = pk;
    }
    #pragma unroll
    for (int kc = 0; kc < 2; ++kc) {
      bf16x8 pa = *(const bf16x8*)&Pls[w][fr][kc * 32 + fq * 8];
      #pragma unroll
      for (int g2 = 0; g2 < 4; ++g2) {
        bf16x8 vf = swz_read(Vls[cur], g2 * 16 + fr, kc * 64 + fq * 16);
        o[g2] = MFMA(pa, vf, o[g2]);
      }
    }
    __syncthreads();  // all reads of cur done + everyone's stage loads landed
    cur ^= 1;
  }

  const float inv = 1.f / fmaxf(s_r, 1e-30f);
  float invr[4];
  #pragma unroll
  for (int r = 0; r < 4; ++r) invr[r] = __shfl(inv, fq * 4 + r, 64);
  const int b = bh >> 4, h = bh & 15;
  #pragma unroll
  for (int r = 0; r < 4; ++r) {
    const int tok = b * 2048 + q0 + fq * 4 + r;
    #pragma unroll
    for (int g2 = 0; g2 < 4; ++g2)
      CTX[(size_t)tok * 1024 + h * 64 + g2 * 16 + fr] =
          (bf16)(o[g2][r] * invr[r]);
  }
}

// ---------------------------------------------------------------------------
// Output projection: out = ctx @ Wo^T + bo. grid = (32, 8).
// ---------------------------------------------------------------------------
__global__ __launch_bounds__(256, 3) void out_kernel(
    const bf16* __restrict__ CTXi, const bf16* __restrict__ Wo,
    const bf16* __restrict__ bo, void* __restrict__ Y,
    const int* __restrict__ flag)
{
  const int isf = *flag;
  const int bm = blockIdx.x * 128, bn = blockIdx.y * 128;
  f32x4 acc[4][4];
  gemm128_core(CTXi, Wo, bm, bn, acc);

  const int t = threadIdx.x, lane = t & 63, w = t >> 6;
  const int wr = w >> 1, wc = w & 1;
  const int fr = lane & 15, fq = lane >> 4;

  #pragma unroll
  for (int n = 0; n < 4; ++n) {
    const int col = bn + wc * 64 + n * 16 + fr;
    const float bb = (float)bo[col];
    #pragma unroll
    for (int m = 0; m < 4; ++m)
      #pragma unroll
      for (int r = 0; r < 4; ++r) {
        const int row = bm + wr * 64 + m * 16 + fq * 4 + r;
        const size_t idx = (size_t)row * 1024 + col;
        const float v = acc[m][n][r] + bb;
        if (isf) ((float*)Y)[idx] = v;
        else     ((bf16*)Y)[idx] = (bf16)v;
      }
  }
}

// ---------------------------------------------------------------------------
extern "C" void kernel_launch(void* const* d_in, const int* in_sizes, int n_in,
                              void* d_out, int out_size, void* d_ws, size_t ws_size,
                              hipStream_t stream) {
  char* ws = (char*)d_ws;
  const size_t MB = 1024 * 1024;

  int*  flag = (int*)ws;
  bf16* cX  = (bf16*)(ws + 1 * MB);
  bf16* cWq = (bf16*)(ws + 9 * MB);
  bf16* cWk = (bf16*)(ws + 11 * MB);
  bf16* cWv = (bf16*)(ws + 13 * MB);
  bf16* cWo = (bf16*)(ws + 15 * MB);
  bf16* cB  = (bf16*)(ws + 17 * MB);   // [4][1024]: q,k,v,o
  bf16* Qw  = (bf16*)(ws + 18 * MB);
  bf16* Kw  = (bf16*)(ws + 26 * MB);
  bf16* Vt  = (bf16*)(ws + 34 * MB);
  bf16* CT  = (bf16*)(ws + 42 * MB);

  detect_kernel<<<1, 128, 0, stream>>>((const unsigned short*)d_in[2], flag);
  cvt_all_kernel<<<2048, 256, 0, stream>>>(d_in[0], d_in[1], d_in[3], d_in[5],
                                           d_in[7], d_in[2], d_in[4], d_in[6],
                                           d_in[8], cX, cWq, cWk, cWv, cWo, cB,
                                           flag);

  qkv_kernel<<<dim3(32, 8, 3), 256, 0, stream>>>(cX, cWq, cWk, cWv, cB,
                                                 Qw, Kw, Vt);
  attn_kernel<<<dim3(32, 32), 256, 0, stream>>>(Qw, Kw, Vt, CT);
  out_kernel<<<dim3(32, 8), 256, 0, stream>>>(CT, cWo, cB + 3072, d_out, flag);
}

// Round 5
// 145.010 us; speedup vs baseline: 2.7220x; 1.1109x over previous
//
#include <hip/hip_runtime.h>
#include <hip/hip_bf16.h>
#include <math.h>

typedef __bf16 bf16;
typedef __bf16 bf16x4 __attribute__((ext_vector_type(4)));
typedef __bf16 bf16x8 __attribute__((ext_vector_type(8)));
typedef float  f32x4  __attribute__((ext_vector_type(4)));
typedef float  float4v __attribute__((ext_vector_type(4)));
typedef unsigned short u16x4 __attribute__((ext_vector_type(4)));

#define MFMA(a,b,c) __builtin_amdgcn_mfma_f32_16x16x32_bf16((a),(b),(c),0,0,0)

// Q is pre-scaled by 1/sqrt(64) * log2(e) -> scores are in log2 domain.
#define QSCALE 0.18033688011112042f

__device__ __forceinline__ void gload16(const bf16* g, bf16* l) {
  __builtin_amdgcn_global_load_lds(
      (const __attribute__((address_space(1))) void*)g,
      (__attribute__((address_space(3))) void*)l, 16, 0, 0);
}

// ---------------------------------------------------------------------------
// Dtype detection (verified: inputs are fp32; flag=1 -> fp32).
// ---------------------------------------------------------------------------
__global__ void detect_kernel(const unsigned short* __restrict__ wqb,
                              int* __restrict__ flag) {
  __shared__ int s;
  if (threadIdx.x == 0) s = 0;
  __syncthreads();
  const float x = __uint_as_float(((unsigned)wqb[threadIdx.x]) << 16);
  if (!(fabsf(x) <= 0.5f)) atomicOr(&s, 1);
  __syncthreads();
  if (threadIdx.x == 0) *flag = s;
}

// ---------------------------------------------------------------------------
// One fused convert for all 9 inputs (float4-vectorized, grid-stride).
// ---------------------------------------------------------------------------
__global__ void cvt_all_kernel(const void* x, const void* wq, const void* wk,
                               const void* wv, const void* wo,
                               const void* bq, const void* bk, const void* bv,
                               const void* bo,
                               bf16* cX, bf16* cWq, bf16* cWk, bf16* cWv,
                               bf16* cWo, bf16* cB, const int* __restrict__ flag)
{
  const int isf = *flag;
  const int NX = 1048576, NW = 262144, NB = 256;  // in 4-element groups
  const int total = NX + 4 * NW + 4 * NB;
  for (int gid = blockIdx.x * blockDim.x + threadIdx.x; gid < total;
       gid += gridDim.x * blockDim.x) {
    const void* s; bf16* d; int off;
    if (gid < NX)                { s = x;  d = cX;  off = gid; }
    else if (gid < NX + NW)      { s = wq; d = cWq; off = gid - NX; }
    else if (gid < NX + 2 * NW)  { s = wk; d = cWk; off = gid - NX - NW; }
    else if (gid < NX + 3 * NW)  { s = wv; d = cWv; off = gid - NX - 2 * NW; }
    else if (gid < NX + 4 * NW)  { s = wo; d = cWo; off = gid - NX - 3 * NW; }
    else {
      const int r = gid - NX - 4 * NW;
      const int wb = r / NB; off = r % NB;
      s = (wb == 0) ? bq : (wb == 1) ? bk : (wb == 2) ? bv : bo;
      d = cB + wb * 1024;
    }
    float4v v;
    if (isf) v = ((const float4v*)s)[off];
    else {
      u16x4 u = ((const u16x4*)s)[off];
      v = (float4v){__uint_as_float((unsigned)u.x << 16),
                    __uint_as_float((unsigned)u.y << 16),
                    __uint_as_float((unsigned)u.z << 16),
                    __uint_as_float((unsigned)u.w << 16)};
    }
    bf16x4 ov = {(bf16)v.x, (bf16)v.y, (bf16)v.z, (bf16)v.w};
    *(bf16x4*)&d[off * 4] = ov;
  }
}

// ---------------------------------------------------------------------------
// 128x128-tile GEMM core (m97 structure): Y[M,N] = X[M,K] @ W[N,K]^T, K=1024.
// ---------------------------------------------------------------------------
static __device__ __forceinline__ void gemm128_core(
    const bf16* __restrict__ X, const bf16* __restrict__ W,
    int bm, int bn, f32x4 acc[4][4])
{
  __shared__ __align__(16) bf16 Als[128][64];
  __shared__ __align__(16) bf16 Bls[128][64];
  const int t    = threadIdx.x;
  const int lane = t & 63;
  const int w    = t >> 6;
  const int wr   = w >> 1, wc = w & 1;
  const int fr   = lane & 15;
  const int fq   = lane >> 4;
  const int lrow = lane >> 3;
  const int lcol = (lane & 7) * 8;

  #pragma unroll
  for (int m = 0; m < 4; ++m)
    #pragma unroll
    for (int n = 0; n < 4; ++n)
      acc[m][n] = (f32x4){0.f, 0.f, 0.f, 0.f};

  for (int k0 = 0; k0 < 1024; k0 += 64) {
    __syncthreads();
    #pragma unroll
    for (int p = 0; p < 4; ++p) {
      const int rb = p * 32 + w * 8;
      gload16(&X[(size_t)(bm + rb + lrow) * 1024 + k0 + lcol], &Als[rb][0]);
      gload16(&W[(size_t)(bn + rb + lrow) * 1024 + k0 + lcol], &Bls[rb][0]);
    }
    __syncthreads();
    #pragma unroll
    for (int kk = 0; kk < 64; kk += 32) {
      bf16x8 a[4], b[4];
      #pragma unroll
      for (int m = 0; m < 4; ++m)
        a[m] = *(const bf16x8*)&Als[wr * 64 + m * 16 + fr][kk + fq * 8];
      #pragma unroll
      for (int n = 0; n < 4; ++n)
        b[n] = *(const bf16x8*)&Bls[wc * 64 + n * 16 + fr][kk + fq * 8];
      #pragma unroll
      for (int m = 0; m < 4; ++m)
        #pragma unroll
        for (int n = 0; n < 4; ++n)
          acc[m][n] = MFMA(a[m], b[n], acc[m][n]);
    }
  }
}

// ---------------------------------------------------------------------------
// QKV projection. grid = (32, 8, 3). z: 0->Q (pre-scaled by QSCALE),
// 1->K ([B,H,L,64]), 2->V^T ([B,H,64,L]).
// ---------------------------------------------------------------------------
__global__ __launch_bounds__(256, 3) void qkv_kernel(
    const bf16* __restrict__ X,
    const bf16* __restrict__ Wq, const bf16* __restrict__ Wk,
    const bf16* __restrict__ Wv, const bf16* __restrict__ Bias,
    bf16* __restrict__ Qo, bf16* __restrict__ Ko, bf16* __restrict__ Vto)
{
  const bf16 *W, *bias;
  bf16 *out;
  const int z = blockIdx.z;
  if (z == 0)      { W = Wq; bias = Bias;        out = Qo;  }
  else if (z == 1) { W = Wk; bias = Bias + 1024; out = Ko;  }
  else             { W = Wv; bias = Bias + 2048; out = Vto; }

  const int bm = blockIdx.x * 128, bn = blockIdx.y * 128;
  f32x4 acc[4][4];
  gemm128_core(X, W, bm, bn, acc);

  const int t = threadIdx.x, lane = t & 63, w = t >> 6;
  const int wr = w >> 1, wc = w & 1;
  const int fr = lane & 15, fq = lane >> 4;
  const float qs = (z == 0) ? QSCALE : 1.0f;

  #pragma unroll
  for (int n = 0; n < 4; ++n) {
    const int col = bn + wc * 64 + n * 16 + fr;
    const float bb = (float)bias[col];
    const int h = col >> 6, d = col & 63;
    if (z != 2) {
      #pragma unroll
      for (int m = 0; m < 4; ++m)
        #pragma unroll
        for (int r = 0; r < 4; ++r) {
          const int row = bm + wr * 64 + m * 16 + fq * 4 + r;
          const int b = row >> 11, li = row & 2047;
          out[(size_t)((b * 16 + h) * 2048 + li) * 64 + d] =
              (bf16)((acc[m][n][r] + bb) * qs);
        }
    } else {
      #pragma unroll
      for (int m = 0; m < 4; ++m) {
        const int tok0 = bm + wr * 64 + m * 16 + fq * 4;
        const int b = tok0 >> 11, li0 = tok0 & 2047;
        bf16x4 pk = {(bf16)(acc[m][n][0] + bb), (bf16)(acc[m][n][1] + bb),
                     (bf16)(acc[m][n][2] + bb), (bf16)(acc[m][n][3] + bb)};
        *(bf16x4*)&out[(size_t)((b * 16 + h) * 64 + d) * 2048 + li0] = pk;
      }
    }
  }
}

// ---------------------------------------------------------------------------
// Attention LDS helpers (rule #21: linear dest + inverse-swizzled source).
// ---------------------------------------------------------------------------
__device__ __forceinline__ void stage8(const bf16* __restrict__ gK,
                                       const bf16* __restrict__ gV,
                                       int kbase, bf16 (*Kl)[64],
                                       bf16 (*Vl)[64], int w, int lane) {
  const int r8 = lane >> 3;            // 0..7
  const int cb = (lane & 7) << 4;      // byte col
  const int row = w * 8 + r8;
  const int sc = (cb ^ ((row & 7) << 4)) >> 1;  // pre-swizzled element col
  gload16(&gK[(size_t)(kbase + row) * 64 + sc], &Kl[w * 8][0]);
  gload16(&gV[(size_t)row * 2048 + kbase + sc], &Vl[w * 8][0]);
}

__device__ __forceinline__ bf16x8 swz_read(const bf16 (*Tl)[64], int row,
                                           int colb) {
  const char* p = (const char*)(&Tl[0][0]) + row * 128 +
                  (colb ^ ((row & 7) << 4));
  return *(const bf16x8*)p;
}

// ---------------------------------------------------------------------------
// Causal flash attention. grid = (16 qtiles, 32 bh), 512 threads = 8 waves.
// QBLK=128 (16 q/wave), KVBLK=64 double-buffered in LDS. Swapped QK^T
// (lane owns one query), exp2-domain softmax, defer-max (shuffle-free
// common path), per-lane partial sums reduced once at the end.
// ---------------------------------------------------------------------------
__global__ __launch_bounds__(512, 4) void attn_kernel(
    const bf16* __restrict__ Q, const bf16* __restrict__ K,
    const bf16* __restrict__ Vt, bf16* __restrict__ CTX)
{
  const int qt = 15 - (int)blockIdx.x;  // heavy tiles first
  const int bh = blockIdx.y;
  const int t = threadIdx.x, lane = t & 63, w = t >> 6;
  const int fr = lane & 15, fq = lane >> 4;
  const bf16* Qb = Q  + (size_t)bh * 2048 * 64;
  const bf16* Kb = K  + (size_t)bh * 2048 * 64;
  const bf16* Vb = Vt + (size_t)bh * 64 * 2048;
  const int q0 = qt * 128 + w * 16;
  const int myq = q0 + fr;
  const int nt = 2 * qt + 2;

  __shared__ __align__(16) bf16 Kls[2][64][64];  // 16 KB
  __shared__ __align__(16) bf16 Vls[2][64][64];  // 16 KB
  __shared__ __align__(16) bf16 Pls[8][16][72];  // 18 KB

  const bf16x8 qf0 = *(const bf16x8*)&Qb[(size_t)(q0 + fr) * 64 + fq * 8];
  const bf16x8 qf1 = *(const bf16x8*)&Qb[(size_t)(q0 + fr) * 64 + 32 + fq * 8];

  f32x4 o[4];
  #pragma unroll
  for (int g = 0; g < 4; ++g) o[g] = (f32x4){0.f, 0.f, 0.f, 0.f};
  float m_r = -1e30f;   // running max (log2 domain), per query fr
  float s_part = 0.f;   // per-lane partial softmax sum (query fr)

  stage8(Kb, Vb, 0, Kls[0], Vls[0], w, lane);
  __syncthreads();
  int cur = 0;

  for (int kt = 0; kt < nt; ++kt) {
    if (kt + 1 < nt)
      stage8(Kb, Vb, (kt + 1) * 64, Kls[cur ^ 1], Vls[cur ^ 1], w, lane);

    const int kbase = kt * 64;
    if (kbase <= q0 + 15) {  // wave-uniform: this wave has unmasked work
      // QK^T swapped: D[key][query]; lane holds keys {g*16+fq*4+r}, query fr.
      f32x4 S[4];
      #pragma unroll
      for (int g = 0; g < 4; ++g) {
        const int kr = g * 16 + fr;
        bf16x8 kf0 = swz_read(Kls[cur], kr, fq * 16);
        bf16x8 kf1 = swz_read(Kls[cur], kr, 64 + fq * 16);
        f32x4 s = (f32x4){0.f, 0.f, 0.f, 0.f};
        s = MFMA(kf0, qf0, s);
        s = MFMA(kf1, qf1, s);
        S[g] = s;
      }
      if (kbase + 63 > q0) {  // wave-uniform: diagonal tile, mask needed
        #pragma unroll
        for (int g = 0; g < 4; ++g)
          #pragma unroll
          for (int r = 0; r < 4; ++r)
            S[g][r] = (kbase + g * 16 + fq * 4 + r <= myq) ? S[g][r] : -1e9f;
      }
      // lane-local max + defer-max check (T13)
      float mxl = S[0][0];
      #pragma unroll
      for (int g = 0; g < 4; ++g)
        #pragma unroll
        for (int r = 0; r < 4; ++r) mxl = fmaxf(mxl, S[g][r]);
      if (!__all(mxl <= m_r + 8.f)) {  // rare rescale path
        float mxq = fmaxf(mxl, __shfl_xor(mxl, 16));
        mxq = fmaxf(mxq, __shfl_xor(mxq, 32));
        const float mnew = fmaxf(m_r, mxq);
        const float f = exp2f(m_r - mnew);
        m_r = mnew;
        s_part *= f;
        float frow[4];
        #pragma unroll
        for (int r = 0; r < 4; ++r) frow[r] = __shfl(f, fq * 4 + r, 64);
        #pragma unroll
        for (int g = 0; g < 4; ++g)
          #pragma unroll
          for (int r = 0; r < 4; ++r) o[g][r] *= frow[r];
      }
      // exp2 + accumulate (pure per-lane)
      #pragma unroll
      for (int g = 0; g < 4; ++g)
        #pragma unroll
        for (int r = 0; r < 4; ++r) {
          const float p = exp2f(S[g][r] - m_r);
          S[g][r] = p;
          s_part += p;
        }
      // P -> per-wave LDS (packed b64), then PV from staged V^T
      #pragma unroll
      for (int g = 0; g < 4; ++g) {
        bf16x4 pk = {(bf16)S[g][0], (bf16)S[g][1], (bf16)S[g][2],
                     (bf16)S[g][3]};
        *(bf16x4*)&Pls[w][fr][g * 16 + fq * 4] = pk;
      }
      #pragma unroll
      for (int kc = 0; kc < 2; ++kc) {
        bf16x8 pa = *(const bf16x8*)&Pls[w][fr][kc * 32 + fq * 8];
        #pragma unroll
        for (int g2 = 0; g2 < 4; ++g2) {
          bf16x8 vf = swz_read(Vls[cur], g2 * 16 + fr, kc * 64 + fq * 16);
          o[g2] = MFMA(pa, vf, o[g2]);
        }
      }
    }
    __syncthreads();
    cur ^= 1;
  }

  // final sum reduce (once) + normalize + write
  float s_r = s_part;
  s_r += __shfl_xor(s_r, 16);
  s_r += __shfl_xor(s_r, 32);
  const float inv = 1.f / fmaxf(s_r, 1e-30f);
  float invr[4];
  #pragma unroll
  for (int r = 0; r < 4; ++r) invr[r] = __shfl(inv, fq * 4 + r, 64);
  const int b = bh >> 4, h = bh & 15;
  #pragma unroll
  for (int r = 0; r < 4; ++r) {
    const int tok = b * 2048 + q0 + fq * 4 + r;
    #pragma unroll
    for (int g2 = 0; g2 < 4; ++g2)
      CTX[(size_t)tok * 1024 + h * 64 + g2 * 16 + fr] =
          (bf16)(o[g2][r] * invr[r]);
  }
}

// ---------------------------------------------------------------------------
// Output projection: out = ctx @ Wo^T + bo. grid = (32, 8).
// ---------------------------------------------------------------------------
__global__ __launch_bounds__(256, 3) void out_kernel(
    const bf16* __restrict__ CTXi, const bf16* __restrict__ Wo,
    const bf16* __restrict__ bo, void* __restrict__ Y,
    const int* __restrict__ flag)
{
  const int isf = *flag;
  const int bm = blockIdx.x * 128, bn = blockIdx.y * 128;
  f32x4 acc[4][4];
  gemm128_core(CTXi, Wo, bm, bn, acc);

  const int t = threadIdx.x, lane = t & 63, w = t >> 6;
  const int wr = w >> 1, wc = w & 1;
  const int fr = lane & 15, fq = lane >> 4;

  #pragma unroll
  for (int n = 0; n < 4; ++n) {
    const int col = bn + wc * 64 + n * 16 + fr;
    const float bb = (float)bo[col];
    #pragma unroll
    for (int m = 0; m < 4; ++m)
      #pragma unroll
      for (int r = 0; r < 4; ++r) {
        const int row = bm + wr * 64 + m * 16 + fq * 4 + r;
        const size_t idx = (size_t)row * 1024 + col;
        const float v = acc[m][n][r] + bb;
        if (isf) ((float*)Y)[idx] = v;
        else     ((bf16*)Y)[idx] = (bf16)v;
      }
  }
}

// ---------------------------------------------------------------------------
extern "C" void kernel_launch(void* const* d_in, const int* in_sizes, int n_in,
                              void* d_out, int out_size, void* d_ws, size_t ws_size,
                              hipStream_t stream) {
  char* ws = (char*)d_ws;
  const size_t MB = 1024 * 1024;

  int*  flag = (int*)ws;
  bf16* cX  = (bf16*)(ws + 1 * MB);
  bf16* cWq = (bf16*)(ws + 9 * MB);
  bf16* cWk = (bf16*)(ws + 11 * MB);
  bf16* cWv = (bf16*)(ws + 13 * MB);
  bf16* cWo = (bf16*)(ws + 15 * MB);
  bf16* cB  = (bf16*)(ws + 17 * MB);   // [4][1024]: q,k,v,o
  bf16* Qw  = (bf16*)(ws + 18 * MB);
  bf16* Kw  = (bf16*)(ws + 26 * MB);
  bf16* Vt  = (bf16*)(ws + 34 * MB);
  bf16* CT  = (bf16*)(ws + 42 * MB);

  detect_kernel<<<1, 128, 0, stream>>>((const unsigned short*)d_in[2], flag);
  cvt_all_kernel<<<2048, 256, 0, stream>>>(d_in[0], d_in[1], d_in[3], d_in[5],
                                           d_in[7], d_in[2], d_in[4], d_in[6],
                                           d_in[8], cX, cWq, cWk, cWv, cWo, cB,
                                           flag);

  qkv_kernel<<<dim3(32, 8, 3), 256, 0, stream>>>(cX, cWq, cWk, cWv, cB,
                                                 Qw, Kw, Vt);
  attn_kernel<<<dim3(16, 32), 512, 0, stream>>>(Qw, Kw, Vt, CT);
  out_kernel<<<dim3(32, 8), 256, 0, stream>>>(CT, cWo, cB + 3072, d_out, flag);
}

// Round 6
// 125.012 us; speedup vs baseline: 3.1574x; 1.1600x over previous
//
#include <hip/hip_runtime.h>
#include <hip/hip_bf16.h>
#include <math.h>

typedef __bf16 bf16;
typedef __bf16 bf16x4 __attribute__((ext_vector_type(4)));
typedef __bf16 bf16x8 __attribute__((ext_vector_type(8)));
typedef float  f32x4  __attribute__((ext_vector_type(4)));
typedef float  float4v __attribute__((ext_vector_type(4)));
typedef unsigned short u16x4 __attribute__((ext_vector_type(4)));

#define MFMA(a,b,c) __builtin_amdgcn_mfma_f32_16x16x32_bf16((a),(b),(c),0,0,0)

// Q is pre-scaled by 1/sqrt(64) * log2(e) -> scores are in log2 domain.
#define QSCALE 0.18033688011112042f

__device__ __forceinline__ void gload16(const bf16* g, bf16* l) {
  __builtin_amdgcn_global_load_lds(
      (const __attribute__((address_space(1))) void*)g,
      (__attribute__((address_space(3))) void*)l, 16, 0, 0);
}

// ---------------------------------------------------------------------------
// Inline dtype detection (verified r2: inputs fp32). Reads 32 bf16-viewed
// halves of w_q_b (|x|<~0.08 if truly bf16); fp32 reinterpretation shows
// huge/NaN halves. Wave-uniform result; P(false negative) ~ 1e-10.
// ---------------------------------------------------------------------------
__device__ __forceinline__ int detect_f32(const unsigned short* __restrict__ p) {
  int bad = 0;
  #pragma unroll
  for (int j = 0; j < 32; ++j) {
    const float x = __uint_as_float(((unsigned)p[j]) << 16);
    bad |= !(fabsf(x) <= 0.5f);
  }
  return bad;
}

// ---------------------------------------------------------------------------
// One fused convert for all 9 inputs (float4-vectorized, grid-stride).
// ---------------------------------------------------------------------------
__global__ void cvt_all_kernel(const void* x, const void* wq, const void* wk,
                               const void* wv, const void* wo,
                               const void* bq, const void* bk, const void* bv,
                               const void* bo,
                               bf16* cX, bf16* cWq, bf16* cWk, bf16* cWv,
                               bf16* cWo, bf16* cB)
{
  const int isf = detect_f32((const unsigned short*)bq);
  const int NX = 1048576, NW = 262144, NB = 256;  // in 4-element groups
  const int total = NX + 4 * NW + 4 * NB;
  for (int gid = blockIdx.x * blockDim.x + threadIdx.x; gid < total;
       gid += gridDim.x * blockDim.x) {
    const void* s; bf16* d; int off;
    if (gid < NX)                { s = x;  d = cX;  off = gid; }
    else if (gid < NX + NW)      { s = wq; d = cWq; off = gid - NX; }
    else if (gid < NX + 2 * NW)  { s = wk; d = cWk; off = gid - NX - NW; }
    else if (gid < NX + 3 * NW)  { s = wv; d = cWv; off = gid - NX - 2 * NW; }
    else if (gid < NX + 4 * NW)  { s = wo; d = cWo; off = gid - NX - 3 * NW; }
    else {
      const int r = gid - NX - 4 * NW;
      const int wb = r / NB; off = r % NB;
      s = (wb == 0) ? bq : (wb == 1) ? bk : (wb == 2) ? bv : bo;
      d = cB + wb * 1024;
    }
    float4v v;
    if (isf) v = ((const float4v*)s)[off];
    else {
      u16x4 u = ((const u16x4*)s)[off];
      v = (float4v){__uint_as_float((unsigned)u.x << 16),
                    __uint_as_float((unsigned)u.y << 16),
                    __uint_as_float((unsigned)u.z << 16),
                    __uint_as_float((unsigned)u.w << 16)};
    }
    bf16x4 ov = {(bf16)v.x, (bf16)v.y, (bf16)v.z, (bf16)v.w};
    *(bf16x4*)&d[off * 4] = ov;
  }
}

// ---------------------------------------------------------------------------
// 128x128-tile GEMM core (m97 structure): Y[M,N] = X[M,K] @ W[N,K]^T, K=1024.
// ---------------------------------------------------------------------------
static __device__ __forceinline__ void gemm128_core(
    const bf16* __restrict__ X, const bf16* __restrict__ W,
    int bm, int bn, f32x4 acc[4][4])
{
  __shared__ __align__(16) bf16 Als[128][64];
  __shared__ __align__(16) bf16 Bls[128][64];
  const int t    = threadIdx.x;
  const int lane = t & 63;
  const int w    = t >> 6;
  const int wr   = w >> 1, wc = w & 1;
  const int fr   = lane & 15;
  const int fq   = lane >> 4;
  const int lrow = lane >> 3;
  const int lcol = (lane & 7) * 8;

  #pragma unroll
  for (int m = 0; m < 4; ++m)
    #pragma unroll
    for (int n = 0; n < 4; ++n)
      acc[m][n] = (f32x4){0.f, 0.f, 0.f, 0.f};

  for (int k0 = 0; k0 < 1024; k0 += 64) {
    __syncthreads();
    #pragma unroll
    for (int p = 0; p < 4; ++p) {
      const int rb = p * 32 + w * 8;
      gload16(&X[(size_t)(bm + rb + lrow) * 1024 + k0 + lcol], &Als[rb][0]);
      gload16(&W[(size_t)(bn + rb + lrow) * 1024 + k0 + lcol], &Bls[rb][0]);
    }
    __syncthreads();
    #pragma unroll
    for (int kk = 0; kk < 64; kk += 32) {
      bf16x8 a[4], b[4];
      #pragma unroll
      for (int m = 0; m < 4; ++m)
        a[m] = *(const bf16x8*)&Als[wr * 64 + m * 16 + fr][kk + fq * 8];
      #pragma unroll
      for (int n = 0; n < 4; ++n)
        b[n] = *(const bf16x8*)&Bls[wc * 64 + n * 16 + fr][kk + fq * 8];
      __builtin_amdgcn_s_setprio(1);
      #pragma unroll
      for (int m = 0; m < 4; ++m)
        #pragma unroll
        for (int n = 0; n < 4; ++n)
          acc[m][n] = MFMA(a[m], b[n], acc[m][n]);
      __builtin_amdgcn_s_setprio(0);
    }
  }
}

// ---------------------------------------------------------------------------
// QKV projection. grid = (32, 8, 3). z: 0->Q (pre-scaled by QSCALE),
// 1->K ([B,H,L,64]), 2->V^T ([B,H,64,L]).
// ---------------------------------------------------------------------------
__global__ __launch_bounds__(256, 3) void qkv_kernel(
    const bf16* __restrict__ X,
    const bf16* __restrict__ Wq, const bf16* __restrict__ Wk,
    const bf16* __restrict__ Wv, const bf16* __restrict__ Bias,
    bf16* __restrict__ Qo, bf16* __restrict__ Ko, bf16* __restrict__ Vto)
{
  const bf16 *W, *bias;
  bf16 *out;
  const int z = blockIdx.z;
  if (z == 0)      { W = Wq; bias = Bias;        out = Qo;  }
  else if (z == 1) { W = Wk; bias = Bias + 1024; out = Ko;  }
  else             { W = Wv; bias = Bias + 2048; out = Vto; }

  const int bm = blockIdx.x * 128, bn = blockIdx.y * 128;
  f32x4 acc[4][4];
  gemm128_core(X, W, bm, bn, acc);

  const int t = threadIdx.x, lane = t & 63, w = t >> 6;
  const int wr = w >> 1, wc = w & 1;
  const int fr = lane & 15, fq = lane >> 4;
  const float qs = (z == 0) ? QSCALE : 1.0f;

  #pragma unroll
  for (int n = 0; n < 4; ++n) {
    const int col = bn + wc * 64 + n * 16 + fr;
    const float bb = (float)bias[col];
    const int h = col >> 6, d = col & 63;
    if (z != 2) {
      #pragma unroll
      for (int m = 0; m < 4; ++m)
        #pragma unroll
        for (int r = 0; r < 4; ++r) {
          const int row = bm + wr * 64 + m * 16 + fq * 4 + r;
          const int b = row >> 11, li = row & 2047;
          out[(size_t)((b * 16 + h) * 2048 + li) * 64 + d] =
              (bf16)((acc[m][n][r] + bb) * qs);
        }
    } else {
      #pragma unroll
      for (int m = 0; m < 4; ++m) {
        const int tok0 = bm + wr * 64 + m * 16 + fq * 4;
        const int b = tok0 >> 11, li0 = tok0 & 2047;
        bf16x4 pk = {(bf16)(acc[m][n][0] + bb), (bf16)(acc[m][n][1] + bb),
                     (bf16)(acc[m][n][2] + bb), (bf16)(acc[m][n][3] + bb)};
        *(bf16x4*)&out[(size_t)((b * 16 + h) * 64 + d) * 2048 + li0] = pk;
      }
    }
  }
}

// ---------------------------------------------------------------------------
// Attention LDS helpers (rule #21: linear dest + inverse-swizzled source).
// ---------------------------------------------------------------------------
__device__ __forceinline__ void stage4(const bf16* __restrict__ gK,
                                       const bf16* __restrict__ gV,
                                       int kbase, bf16 (*Kl)[64],
                                       bf16 (*Vl)[64], int w, int lane) {
  const int r8 = lane >> 3;            // 0..7
  const int cb = (lane & 7) << 4;      // byte col
  #pragma unroll
  for (int p = 0; p < 2; ++p) {
    const int row = p * 32 + w * 8 + r8;
    const int sc = (cb ^ ((row & 7) << 4)) >> 1;  // pre-swizzled element col
    gload16(&gK[(size_t)(kbase + row) * 64 + sc], &Kl[p * 32 + w * 8][0]);
    gload16(&gV[(size_t)row * 2048 + kbase + sc], &Vl[p * 32 + w * 8][0]);
  }
}

__device__ __forceinline__ bf16x8 swz_read(const bf16 (*Tl)[64], int row,
                                           int colb) {
  const char* p = (const char*)(&Tl[0][0]) + row * 128 +
                  (colb ^ ((row & 7) << 4));
  return *(const bf16x8*)p;
}

__device__ __forceinline__ f32x4 fmax4(f32x4 a, f32x4 b) {
  return (f32x4){fmaxf(a[0], b[0]), fmaxf(a[1], b[1]),
                 fmaxf(a[2], b[2]), fmaxf(a[3], b[3])};
}

// ---------------------------------------------------------------------------
// Process one 64-row q-tile (4 waves x 16 queries). Swapped QK^T (lane owns
// one query), exp2-domain online softmax with defer-max, double-buffered
// K/V tiles in LDS.
// ---------------------------------------------------------------------------
__device__ __forceinline__ void run_qtile(
    int qt, int bh, int w, int lane, int fr, int fq,
    const bf16* __restrict__ Qb, const bf16* __restrict__ Kb,
    const bf16* __restrict__ Vb, bf16* __restrict__ CTX,
    bf16 (*Kls)[64][64], bf16 (*Vls)[64][64], bf16 (*Pls)[16][72])
{
  const int q0 = qt * 64 + w * 16;
  const int myq = q0 + fr;
  const int nt = qt + 1;

  const bf16x8 qf0 = *(const bf16x8*)&Qb[(size_t)(q0 + fr) * 64 + fq * 8];
  const bf16x8 qf1 = *(const bf16x8*)&Qb[(size_t)(q0 + fr) * 64 + 32 + fq * 8];

  f32x4 o[4];
  #pragma unroll
  for (int g = 0; g < 4; ++g) o[g] = (f32x4){0.f, 0.f, 0.f, 0.f};
  float m_r = -1e30f;   // running max (log2 domain) for query fr
  float s_part = 0.f;   // per-lane partial sum for query fr

  stage4(Kb, Vb, 0, Kls[0], Vls[0], w, lane);
  __syncthreads();
  int cur = 0;

  for (int kt = 0; kt < nt; ++kt) {
    if (kt + 1 < nt)
      stage4(Kb, Vb, (kt + 1) * 64, Kls[cur ^ 1], Vls[cur ^ 1], w, lane);

    const int kbase = kt * 64;
    // QK^T swapped: D[key][query]; lane holds keys {g*16+fq*4+r}, query fr.
    f32x4 S[4];
    __builtin_amdgcn_s_setprio(1);
    #pragma unroll
    for (int g = 0; g < 4; ++g) {
      const int kr = g * 16 + fr;
      bf16x8 kf0 = swz_read(Kls[cur], kr, fq * 16);
      bf16x8 kf1 = swz_read(Kls[cur], kr, 64 + fq * 16);
      f32x4 s = (f32x4){0.f, 0.f, 0.f, 0.f};
      s = MFMA(kf0, qf0, s);
      s = MFMA(kf1, qf1, s);
      S[g] = s;
    }
    __builtin_amdgcn_s_setprio(0);

    if (kt == qt) {  // the single diagonal tile needs masking
      #pragma unroll
      for (int g = 0; g < 4; ++g)
        #pragma unroll
        for (int r = 0; r < 4; ++r)
          S[g][r] = (kbase + g * 16 + fq * 4 + r <= myq) ? S[g][r] : -1e9f;
    }
    // lane-local max (tree) + defer-max (T13)
    f32x4 mv = fmax4(fmax4(S[0], S[1]), fmax4(S[2], S[3]));
    const float mxl = fmaxf(fmaxf(mv[0], mv[1]), fmaxf(mv[2], mv[3]));
    if (!__all(mxl <= m_r + 8.f)) {  // rare rescale path
      float mxq = fmaxf(mxl, __shfl_xor(mxl, 16));
      mxq = fmaxf(mxq, __shfl_xor(mxq, 32));
      const float mnew = fmaxf(m_r, mxq);
      const float f = exp2f(m_r - mnew);
      m_r = mnew;
      s_part *= f;
      float frow[4];
      #pragma unroll
      for (int r = 0; r < 4; ++r) frow[r] = __shfl(f, fq * 4 + r, 64);
      #pragma unroll
      for (int g = 0; g < 4; ++g)
        #pragma unroll
        for (int r = 0; r < 4; ++r) o[g][r] *= frow[r];
    }
    // exp2 + accumulate (pure per-lane)
    #pragma unroll
    for (int g = 0; g < 4; ++g)
      #pragma unroll
      for (int r = 0; r < 4; ++r) {
        const float p = exp2f(S[g][r] - m_r);
        S[g][r] = p;
        s_part += p;
      }
    // P -> per-wave LDS (packed b64), then PV from staged V^T
    #pragma unroll
    for (int g = 0; g < 4; ++g) {
      bf16x4 pk = {(bf16)S[g][0], (bf16)S[g][1], (bf16)S[g][2], (bf16)S[g][3]};
      *(bf16x4*)&Pls[w][fr][g * 16 + fq * 4] = pk;
    }
    __builtin_amdgcn_s_setprio(1);
    #pragma unroll
    for (int kc = 0; kc < 2; ++kc) {
      bf16x8 pa = *(const bf16x8*)&Pls[w][fr][kc * 32 + fq * 8];
      #pragma unroll
      for (int g2 = 0; g2 < 4; ++g2) {
        bf16x8 vf = swz_read(Vls[cur], g2 * 16 + fr, kc * 64 + fq * 16);
        o[g2] = MFMA(pa, vf, o[g2]);
      }
    }
    __builtin_amdgcn_s_setprio(0);
    __syncthreads();
    cur ^= 1;
  }

  // final sum reduce + normalize + write
  float s_r = s_part;
  s_r += __shfl_xor(s_r, 16);
  s_r += __shfl_xor(s_r, 32);
  const float inv = 1.f / fmaxf(s_r, 1e-30f);
  float invr[4];
  #pragma unroll
  for (int r = 0; r < 4; ++r) invr[r] = __shfl(inv, fq * 4 + r, 64);
  const int b = bh >> 4, h = bh & 15;
  #pragma unroll
  for (int r = 0; r < 4; ++r) {
    const int tok = b * 2048 + q0 + fq * 4 + r;
    #pragma unroll
    for (int g2 = 0; g2 < 4; ++g2)
      CTX[(size_t)tok * 1024 + h * 64 + g2 * 16 + fr] =
          (bf16)(o[g2][r] * invr[r]);
  }
}

// ---------------------------------------------------------------------------
// Causal flash attention. grid = (16, 32 bh), 256 threads = 4 waves.
// Deterministic load balance: block x handles q-tiles {31-x, x} ->
// (32-x)+(x+1) = 33 K-tile rounds per block, uniform across all 512 blocks.
// ---------------------------------------------------------------------------
__global__ __launch_bounds__(256, 3) void attn_kernel(
    const bf16* __restrict__ Q, const bf16* __restrict__ K,
    const bf16* __restrict__ Vt, bf16* __restrict__ CTX)
{
  const int x = (int)blockIdx.x;
  const int bh = blockIdx.y;
  const int t = threadIdx.x, lane = t & 63, w = t >> 6;
  const int fr = lane & 15, fq = lane >> 4;
  const bf16* Qb = Q  + (size_t)bh * 2048 * 64;
  const bf16* Kb = K  + (size_t)bh * 2048 * 64;
  const bf16* Vb = Vt + (size_t)bh * 64 * 2048;

  __shared__ __align__(16) bf16 Kls[2][64][64];  // 16 KB
  __shared__ __align__(16) bf16 Vls[2][64][64];  // 16 KB
  __shared__ __align__(16) bf16 Pls[4][16][72];  // 9 KB

  run_qtile(31 - x, bh, w, lane, fr, fq, Qb, Kb, Vb, CTX, Kls, Vls, Pls);
  run_qtile(x,      bh, w, lane, fr, fq, Qb, Kb, Vb, CTX, Kls, Vls, Pls);
}

// ---------------------------------------------------------------------------
// Output projection: out = ctx @ Wo^T + bo. grid = (32, 8).
// ---------------------------------------------------------------------------
__global__ __launch_bounds__(256, 3) void out_kernel(
    const bf16* __restrict__ CTXi, const bf16* __restrict__ Wo,
    const bf16* __restrict__ bo, void* __restrict__ Y,
    const unsigned short* __restrict__ det)
{
  const int isf = detect_f32(det);
  const int bm = blockIdx.x * 128, bn = blockIdx.y * 128;
  f32x4 acc[4][4];
  gemm128_core(CTXi, Wo, bm, bn, acc);

  const int t = threadIdx.x, lane = t & 63, w = t >> 6;
  const int wr = w >> 1, wc = w & 1;
  const int fr = lane & 15, fq = lane >> 4;

  #pragma unroll
  for (int n = 0; n < 4; ++n) {
    const int col = bn + wc * 64 + n * 16 + fr;
    const float bb = (float)bo[col];
    #pragma unroll
    for (int m = 0; m < 4; ++m)
      #pragma unroll
      for (int r = 0; r < 4; ++r) {
        const int row = bm + wr * 64 + m * 16 + fq * 4 + r;
        const size_t idx = (size_t)row * 1024 + col;
        const float v = acc[m][n][r] + bb;
        if (isf) ((float*)Y)[idx] = v;
        else     ((bf16*)Y)[idx] = (bf16)v;
      }
  }
}

// ---------------------------------------------------------------------------
extern "C" void kernel_launch(void* const* d_in, const int* in_sizes, int n_in,
                              void* d_out, int out_size, void* d_ws, size_t ws_size,
                              hipStream_t stream) {
  char* ws = (char*)d_ws;
  const size_t MB = 1024 * 1024;

  bf16* cX  = (bf16*)(ws + 1 * MB);
  bf16* cWq = (bf16*)(ws + 9 * MB);
  bf16* cWk = (bf16*)(ws + 11 * MB);
  bf16* cWv = (bf16*)(ws + 13 * MB);
  bf16* cWo = (bf16*)(ws + 15 * MB);
  bf16* cB  = (bf16*)(ws + 17 * MB);   // [4][1024]: q,k,v,o
  bf16* Qw  = (bf16*)(ws + 18 * MB);
  bf16* Kw  = (bf16*)(ws + 26 * MB);
  bf16* Vt  = (bf16*)(ws + 34 * MB);
  bf16* CT  = (bf16*)(ws + 42 * MB);

  cvt_all_kernel<<<2048, 256, 0, stream>>>(d_in[0], d_in[1], d_in[3], d_in[5],
                                           d_in[7], d_in[2], d_in[4], d_in[6],
                                           d_in[8], cX, cWq, cWk, cWv, cWo, cB);

  qkv_kernel<<<dim3(32, 8, 3), 256, 0, stream>>>(cX, cWq, cWk, cWv, cB,
                                                 Qw, Kw, Vt);
  attn_kernel<<<dim3(16, 32), 256, 0, stream>>>(Qw, Kw, Vt, CT);
  out_kernel<<<dim3(32, 8), 256, 0, stream>>>(CT, cWo, cB + 3072, d_out,
                                              (const unsigned short*)d_in[2]);
}